// Round 6
// baseline (83.781 us; speedup 1.0000x reference)
//
#include <hip/hip_runtime.h>

// Problem constants (from reference setup_inputs)
constexpr int cB = 32, cC = 6, cT = 64;
constexpr int cK = 8, cN = 128;
constexpr int cS = 32, cP = 64;
constexpr int NSEG_PAD = cK * cN;     // 1024 slots; n==127 are pads
constexpr int NCL  = cS * cP;         // 2048 centerline points per batch
constexpr int G = 4;                  // blocks per (b,c); 16 points per block
constexpr int PPW = 4;                // points per wave (register-blocked)
constexpr int NIT = NSEG_PAD / 64;    // 16 iterations per lane
constexpr float F_EPS = 1e-6f;
constexpr float F_THRESHOLD = 0.5f;

// 768 blocks (3/CU), 4 waves/block, 4 points/wave. Segment/centerline loads
// are software-pipelined one iteration ahead so L1/L2 latency hides behind
// the ~100-instr register-blocked ALU body.
__global__ __launch_bounds__(256) void offroad_kernel(
    const float* __restrict__ points,         // (B, C, T, 2)
    const float* __restrict__ road_boundary,  // (B, K, N, 2)
    const float* __restrict__ centerlines,    // (B, S, P, 2)
    float* __restrict__ out)                  // (B, C), pre-zeroed
{
    const int blk  = blockIdx.x;         // 0 .. B*C*G-1
    const int g    = blk & (G - 1);
    const int bc   = blk >> 2;           // b*C + c
    const int b    = bc / cC;
    const int lane = threadIdx.x & 63;
    const int wave = threadIdx.x >> 6;

    const float2* __restrict__ rb2 =
        (const float2*)(road_boundary + (size_t)b * cK * cN * 2);
    const float4* __restrict__ cl4 =
        (const float4*)(centerlines + (size_t)b * NCL * 2);

    // 4 consecutive points for this wave (wave-uniform -> scalar loads)
    const int t0 = (g << 4) | (wave << 2);   // in [0, 64)
    const float* pb = points + (((size_t)bc) * cT + t0) * 2;
    float px[PPW], py[PPW];
    #pragma unroll
    for (int p = 0; p < PPW; ++p) { px[p] = pb[2 * p]; py[p] = pb[2 * p + 1]; }

    // ---- Fused + pipelined: segment distance + centerline argmin ----
    float min_d2[PPW], best_d2[PPW];
    int   best_i[PPW];
    #pragma unroll
    for (int p = 0; p < PPW; ++p) {
        min_d2[p] = 3.4e38f; best_d2[p] = 3.4e38f; best_i[p] = 0x7fffffff;
    }

    int s = lane;
    // prologue loads (pad lanes n==127: s1=s -> d=0 -> endpoint distance,
    // >= adjacent real segment's distance -> min unaffected)
    float2 a  = rb2[s];
    float2 nx = rb2[s + (((s & (cN - 1)) < cN - 1) ? 1 : 0)];
    float4 cp = cl4[s];

    #pragma unroll 4
    for (int i = 0; i < NIT; ++i) {
        const float2 ac = a;  const float2 nxc = nx;  const float4 cpc = cp;
        const int    sc = s;
        s += 64;
        if (i < NIT - 1) {    // prefetch next iteration
            a  = rb2[s];
            nx = rb2[s + (((s & (cN - 1)) < cN - 1) ? 1 : 0)];
            cp = cl4[s];
        }

        const float dx = nxc.x - ac.x, dy = nxc.y - ac.y;
        const float inv_e2 = __builtin_amdgcn_rcpf(dx * dx + dy * dy + F_EPS);
        const int ia = 2 * sc;

        #pragma unroll
        for (int p = 0; p < PPW; ++p) {
            // point-to-segment distance
            float v1x = px[p] - ac.x, v1y = py[p] - ac.y;
            float proj = (v1x * dx + v1y * dy) * inv_e2;
            proj = fminf(fmaxf(proj, 0.0f), 1.0f);
            float ex = v1x - dx * proj;
            float ey = v1y - dy * proj;
            min_d2[p] = fminf(min_d2[p], ex * ex + ey * ey);

            // centerline argmin (first-index tie-break, matches jnp.argmin)
            float dxa = px[p] - cpc.x, dya = py[p] - cpc.y;
            float d2a = dxa * dxa + dya * dya;
            float dxb = px[p] - cpc.z, dyb = py[p] - cpc.w;
            float d2b = dxb * dxb + dyb * dyb;
            float dmin = d2a; int imin = ia;
            if (d2b < d2a) { dmin = d2b; imin = ia + 1; }  // lower idx on tie
            if (dmin < best_d2[p] ||
                (dmin == best_d2[p] && imin < best_i[p])) {
                best_d2[p] = dmin; best_i[p] = imin;
            }
        }
    }

    // argmin butterfly across 64 lanes (tie -> lower index)
    #pragma unroll
    for (int off = 1; off <= 32; off <<= 1) {
        #pragma unroll
        for (int p = 0; p < PPW; ++p) {
            float od2 = __shfl_xor(best_d2[p], off);
            int   oi  = __shfl_xor(best_i[p], off);
            if (od2 < best_d2[p] || (od2 == best_d2[p] && oi < best_i[p])) {
                best_d2[p] = od2; best_i[p] = oi;
            }
        }
    }

    // closest centerline point per point (lane-uniform broadcast loads)
    const float2* __restrict__ cl2 = (const float2*)cl4;
    float dax[PPW], day[PPW];
    #pragma unroll
    for (int p = 0; p < PPW; ++p) {
        float2 cc = cl2[best_i[p]];
        dax[p] = cc.x - px[p]; day[p] = cc.y - py[p];   // da = a2 - a1
    }

    // ---- Segment intersection, pipelined, division-free ----
    // t,u in [0,1] with t=ct/w, u=cu/w, w=dadb+EPS:
    //   0<=t<=1  <=>  ct*w >= 0  &&  ct*w <= w*w   (multiply by w^2 > 0)
    int hit[PPW] = {0, 0, 0, 0};
    s = lane;
    a  = rb2[s];
    nx = rb2[s + (((s & (cN - 1)) < cN - 1) ? 1 : 0)];

    #pragma unroll 4
    for (int i = 0; i < NIT; ++i) {
        const float2 ac = a;  const float2 nxc = nx;
        const int    sc = s;
        s += 64;
        if (i < NIT - 1) {    // prefetch next iteration
            a  = rb2[s];
            nx = rb2[s + (((s & (cN - 1)) < cN - 1) ? 1 : 0)];
        }

        const float dbx = nxc.x - ac.x, dby = nxc.y - ac.y;  // db
        const int valid = ((sc & (cN - 1)) < cN - 1) ? 1 : 0;

        #pragma unroll
        for (int p = 0; p < PPW; ++p) {
            float dpx = px[p] - ac.x, dpy = py[p] - ac.y;    // dp = a1 - b1
            float w  = dax[p] * dby - day[p] * dbx + F_EPS;  // cross(da,db)+EPS
            float w2 = w * w;
            float ct = (dax[p] * dpy - day[p] * dpx) * w;    // cross(da,dp)*w
            float cu = (dbx * dpy - dby * dpx) * w;          // cross(db,dp)*w
            bool inb = (ct >= 0.0f) & (ct <= w2) & (cu >= 0.0f) & (cu <= w2);
            hit[p] |= valid & (int)inb;
        }
    }

    // ---- reduce min_d2 / hit across 64 lanes ----
    #pragma unroll
    for (int off = 1; off <= 32; off <<= 1) {
        #pragma unroll
        for (int p = 0; p < PPW; ++p) {
            min_d2[p] = fminf(min_d2[p], __shfl_xor(min_d2[p], off));
            hit[p]   |= __shfl_xor(hit[p], off);
        }
    }

    // ---- final loss for this wave's 4 points, one atomic per wave ----
    float total = 0.0f;
    #pragma unroll
    for (int p = 0; p < PPW; ++p) {
        float md = sqrtf(min_d2[p]);
        float sd = hit[p] ? md : -md;               // inside -> negative
        total += fmaxf(sd + F_THRESHOLD, 0.0f);
    }
    if (lane == 0)
        atomicAdd(&out[bc], total);
}

extern "C" void kernel_launch(void* const* d_in, const int* in_sizes, int n_in,
                              void* d_out, int out_size, void* d_ws, size_t ws_size,
                              hipStream_t stream) {
    const float* points      = (const float*)d_in[0];
    const float* boundary    = (const float*)d_in[1];
    const float* centerlines = (const float*)d_in[2];
    float* out = (float*)d_out;
    hipMemsetAsync(out, 0, (size_t)out_size * sizeof(float), stream);
    offroad_kernel<<<cB * cC * G, 256, 0, stream>>>(points, boundary, centerlines, out);
}